// Round 3
// baseline (175.246 us; speedup 1.0000x reference)
//
#include <hip/hip_runtime.h>

#define S_TOTAL (512 * 512)     // 262144
#define BATCH 64
#define NR 20                   // N_DEG * RANK
#define NBLK_K1 1024            // 256 s per block
#define NBLK_K2A 128
#define HW 69                   // hrow pitch: gcd(69,32)=1 -> conflict-free

// ---------------------------------------------------------------------------
// k1: fused bilinear-upsample + za partials. 256 thr / block.
// A is wave-uniform -> loaded via s_load_dwordx4 (SGPR operand feeds v_fmac
// directly, zero LDS). Waves split (nr-half x k-half): 10 A-streams per wave.
// hrow (y-lerped input row) staged in LDS, read with rolling registers.
// ---------------------------------------------------------------------------
__global__ __launch_bounds__(256) void za_partial_kernel(
    const float* __restrict__ x,      // (64,1,128,128)
    const float* __restrict__ A,      // (5,4,S)
    float* __restrict__ partial)      // (NBLK_K1, 1280)
{
    __shared__ float hrow[BATCH][HW];   // 17.7 KB
    __shared__ float red[4][640];       // 10.2 KB cross-wave reduce

    const int t    = threadIdx.x;
    const int blk  = blockIdx.x;
    const int y    = blk >> 1;          // output row
    const int half = blk & 1;
    const int s0   = blk << 8;
    const int kst  = half << 6;         // first input col center

    // y-dim bilinear (half-pixel, clamped == jax renormalized edges)
    const float cy  = (y + 0.5f) * 0.25f - 0.5f;
    const float fj  = floorf(cy);
    const int   jy  = (int)fj;
    const float wy1 = cy - fj;
    const float wy0 = 1.0f - wy1;
    const int   j0  = min(max(jy, 0), 127);
    const int   j1  = min(max(jy + 1, 0), 127);

    // phase 1: h[b][col] = wy0*x[b][j0][cin] + wy1*x[b][j1][cin], col 0..65
    for (int e = t; e < BATCH * 66; e += 256) {
        const int b   = e / 66;
        const int col = e - b * 66;
        const int cin = min(max(kst - 1 + col, 0), 127);
        hrow[b][col] = x[b * 16384 + j0 * 128 + cin] * wy0 +
                       x[b * 16384 + j1 * 128 + cin] * wy1;
    }
    __syncthreads();

    // phase 2: lane = batch; wave w = nrh + 2*kh (10 nr's x 32 k-groups)
    const int w    = __builtin_amdgcn_readfirstlane(t >> 6);  // force SGPR
    const int nrh  = w & 1;
    const int kh   = w >> 1;
    const int lane = t & 63;

    float acc[10];
#pragma unroll
    for (int i = 0; i < 10; ++i) acc[i] = 0.0f;

    const int kl0 = kh * 32;
    float h0 = hrow[lane][kl0];
    float h1 = hrow[lane][kl0 + 1];
    const float* Ab = A + (size_t)(nrh * 10) * S_TOTAL + s0;  // uniform base

    for (int kl = kl0; kl < kl0 + 32; ++kl) {
        const float h2 = hrow[lane][kl + 2];
        const float v0 = 0.375f * h0 + 0.625f * h1;
        const float v1 = 0.125f * h0 + 0.875f * h1;
        const float v2 = 0.875f * h1 + 0.125f * h2;
        const float v3 = 0.625f * h1 + 0.375f * h2;
#pragma unroll
        for (int nr = 0; nr < 10; ++nr) {
            // uniform address -> s_load_dwordx4; components are SGPR FMA operands
            const float4 av = *(const float4*)(Ab + (size_t)nr * S_TOTAL + 4 * kl);
            acc[nr] = fmaf(av.x, v0, fmaf(av.y, v1,
                      fmaf(av.z, v2, fmaf(av.w, v3, acc[nr]))));
        }
        h0 = h1; h1 = h2;
    }

#pragma unroll
    for (int nr = 0; nr < 10; ++nr)
        red[w][nr * 64 + lane] = acc[nr];
    __syncthreads();
    for (int i = t; i < 1280; i += 256) {
        const int nr  = i >> 6;
        const int b   = i & 63;
        const int nh  = (nr >= 10) ? 1 : 0;
        const int loc = (nr - nh * 10) * 64 + b;
        partial[(size_t)blk * 1280 + i] = red[nh][loc] + red[2 + nh][loc];
    }
}

// ---------------------------------------------------------------------------
// k2a: reduce 8 k1-partials per block (coalesced columns)
// ---------------------------------------------------------------------------
__global__ __launch_bounds__(256) void za_reduce1_kernel(
    const float* __restrict__ partial, float* __restrict__ partial2)
{
    const int j = blockIdx.x;
    const int t = threadIdx.x;
    for (int c = t; c < 1280; c += 256) {
        float s = 0.0f;
#pragma unroll
        for (int r = 0; r < 8; ++r)
            s += partial[(size_t)(8 * j + r) * 1280 + c];
        partial2[(size_t)j * 1280 + c] = s;
    }
}

// ---------------------------------------------------------------------------
// k2b: final column sum over 128 rows -> za[1280]
// ---------------------------------------------------------------------------
__global__ __launch_bounds__(256) void za_reduce2_kernel(
    const float* __restrict__ partial2, float* __restrict__ za)
{
    const int c = blockIdx.x * 256 + threadIdx.x;
    float s0 = 0.0f, s1 = 0.0f, s2 = 0.0f, s3 = 0.0f;
    for (int r = 0; r < NBLK_K2A; r += 4) {
        s0 += partial2[(size_t)r * 1280 + c];
        s1 += partial2[(size_t)(r + 1) * 1280 + c];
        s2 += partial2[(size_t)(r + 2) * 1280 + c];
        s3 += partial2[(size_t)(r + 3) * 1280 + c];
    }
    za[c] = (s0 + s1) + (s2 + s3);
}

// ---------------------------------------------------------------------------
// k3: z recurrence + out = z*C^T + bias. 512 blocks: 256 s-chunks x 2 b-halves.
// ---------------------------------------------------------------------------
__global__ __launch_bounds__(256) void out_kernel(
    const float* __restrict__ C,      // (S,4)
    const float* __restrict__ bias,   // (S,)
    const float* __restrict__ za,     // (20,64)
    float* __restrict__ out)          // (64,S)
{
    __shared__ float zs[BATCH][4];
    const int t  = threadIdx.x;
    const int sb = blockIdx.x >> 1;   // s-chunk (1024 s)
    const int bh = blockIdx.x & 1;    // batch half

    if (t < 64) {
        const int bb = t;
#pragma unroll
        for (int r = 0; r < 4; ++r) {
            float zv = za[r * 64 + bb];                 // n = 0
#pragma unroll
            for (int n = 1; n < 5; ++n)
                zv *= (1.0f + za[(n * 4 + r) * 64 + bb]);
            zs[bb][r] = zv;
        }
    }
    __syncthreads();

    const int s0 = (sb * 256 + t) * 4;
    const float4 c0 = *(const float4*)(C + (size_t)s0 * 4);
    const float4 c1 = *(const float4*)(C + (size_t)s0 * 4 + 4);
    const float4 c2 = *(const float4*)(C + (size_t)s0 * 4 + 8);
    const float4 c3 = *(const float4*)(C + (size_t)s0 * 4 + 12);
    const float4 bv = *(const float4*)(bias + s0);

#pragma unroll 4
    for (int bb = bh * 32; bb < bh * 32 + 32; ++bb) {
        const float z0 = zs[bb][0], z1 = zs[bb][1];
        const float z2 = zs[bb][2], z3 = zs[bb][3];
        float4 o;
        o.x = fmaf(z0, c0.x, fmaf(z1, c0.y, fmaf(z2, c0.z, fmaf(z3, c0.w, bv.x))));
        o.y = fmaf(z0, c1.x, fmaf(z1, c1.y, fmaf(z2, c1.z, fmaf(z3, c1.w, bv.y))));
        o.z = fmaf(z0, c2.x, fmaf(z1, c2.y, fmaf(z2, c2.z, fmaf(z3, c2.w, bv.z))));
        o.w = fmaf(z0, c3.x, fmaf(z1, c3.y, fmaf(z2, c3.z, fmaf(z3, c3.w, bv.w))));
        *(float4*)(out + (size_t)bb * S_TOTAL + s0) = o;
    }
}

// ---------------------------------------------------------------------------
extern "C" void kernel_launch(void* const* d_in, const int* in_sizes, int n_in,
                              void* d_out, int out_size, void* d_ws, size_t ws_size,
                              hipStream_t stream)
{
    const float* x    = (const float*)d_in[0];
    const float* A    = (const float*)d_in[1];
    const float* C    = (const float*)d_in[2];
    const float* bias = (const float*)d_in[3];
    float* out = (float*)d_out;

    float* partial  = (float*)d_ws;                          // 1024*1280
    float* partial2 = partial + (size_t)NBLK_K1 * 1280;      // 128*1280
    float* za       = partial2 + (size_t)NBLK_K2A * 1280;    // 1280

    za_partial_kernel<<<NBLK_K1, 256, 0, stream>>>(x, A, partial);
    za_reduce1_kernel<<<NBLK_K2A, 256, 0, stream>>>(partial, partial2);
    za_reduce2_kernel<<<5, 256, 0, stream>>>(partial2, za);
    out_kernel<<<512, 256, 0, stream>>>(C, bias, za, out);
}

// Round 4
// 63.538 us; speedup vs baseline: 2.7581x; 2.7581x over previous
//
#include <hip/hip_runtime.h>

#define S_TOTAL (512 * 512)     // 262144
#define BATCH 64
#define NBLK_K1 512             // one output row (512 s = 128 input cols) per block
#define PITCH 130               // hsm cols: input col -1..128 (clamped)

typedef float vfloat4 __attribute__((ext_vector_type(4)));

// gfx9 canonical 6-stage DPP wave64 reduction; total lands in lane 63.
__device__ __forceinline__ float wave_sum63(float s) {
    int v;
    v = __builtin_amdgcn_update_dpp(0, __float_as_int(s), 0x111, 0xf, 0xf, false); // row_shr:1
    s += __int_as_float(v);
    v = __builtin_amdgcn_update_dpp(0, __float_as_int(s), 0x112, 0xf, 0xf, false); // row_shr:2
    s += __int_as_float(v);
    v = __builtin_amdgcn_update_dpp(0, __float_as_int(s), 0x114, 0xf, 0xf, false); // row_shr:4
    s += __int_as_float(v);
    v = __builtin_amdgcn_update_dpp(0, __float_as_int(s), 0x118, 0xf, 0xf, false); // row_shr:8
    s += __int_as_float(v);
    v = __builtin_amdgcn_update_dpp(0, __float_as_int(s), 0x142, 0xa, 0xf, false); // row_bcast:15
    s += __int_as_float(v);
    v = __builtin_amdgcn_update_dpp(0, __float_as_int(s), 0x143, 0xc, 0xf, false); // row_bcast:31
    s += __int_as_float(v);
    return s;
}

// ---------------------------------------------------------------------------
// k1: fused bilinear-upsample + za partials. 512 thr (8 waves), 512 blocks.
// lane = s-position (input col), wave = b-octet. A-frags per-lane-distinct
// ds_read_b128 held in VGPRs, reused across the 8-batch register loop.
// k-reduction: 6-stage DPP per (b,nr); lane 63 stores float4 direct to global.
// ---------------------------------------------------------------------------
__global__ __launch_bounds__(512) void za_partial_kernel(
    const float* __restrict__ x,      // (64,1,128,128)
    const float* __restrict__ A,      // (5,4,S)
    float* __restrict__ partial)      // (NBLK_K1, 1280), elem nr*64+b
{
    __shared__ float hsm[BATCH][PITCH];   // 33.3 KB y-lerped row
    __shared__ float asq[20][512];        // 40 KB A tile

    const int t   = threadIdx.x;
    const int blk = blockIdx.x;
    const int y   = blk;
    const int s0  = blk * 512;

    // y-dim bilinear (half-pixel, clamped == jax renormalized edges)
    const float cy  = (y + 0.5f) * 0.25f - 0.5f;
    const float fj  = floorf(cy);
    const int   jy  = (int)fj;
    const float wy1 = cy - fj;
    const float wy0 = 1.0f - wy1;
    const int   j0  = min(max(jy, 0), 127);
    const int   j1  = min(max(jy + 1, 0), 127);

    // stage h: hsm[b][c] = lerp of input col c-1 (clamped)
#pragma unroll 5
    for (int e = t; e < BATCH * PITCH; e += 512) {
        const int b   = e / PITCH;
        const int col = e - b * PITCH;
        const int cin = min(max(col - 1, 0), 127);
        hsm[b][col] = x[b * 16384 + j0 * 128 + cin] * wy0 +
                      x[b * 16384 + j1 * 128 + cin] * wy1;
    }
    // stage A tile: [20][512] via float4 (5 per thread, coalesced)
#pragma unroll 5
    for (int i = t; i < 20 * 128; i += 512) {
        const int nr = i >> 7;
        const int jq = i & 127;
        *(vfloat4*)&asq[nr][jq * 4] =
            *(const vfloat4*)(A + (size_t)nr * S_TOTAL + s0 + jq * 4);
    }
    __syncthreads();

    const int w    = t >> 6;
    const int lane = t & 63;
    const int b0   = w * 8;

#pragma unroll
    for (int ch = 0; ch < 2; ++ch) {      // nr-chunk of 10
        float acc[8][10];
#pragma unroll
        for (int bi = 0; bi < 8; ++bi)
#pragma unroll
            for (int j = 0; j < 10; ++j) acc[bi][j] = 0.0f;

#pragma unroll
        for (int cs = 0; cs < 2; ++cs) {  // col-step: lane covers cols lane, lane+64
            const int L = lane + 64 * cs;
            float v0[8], v1[8], v2[8], v3[8];
#pragma unroll
            for (int bi = 0; bi < 8; ++bi) {
                const float hl = hsm[b0 + bi][L];
                const float hc = hsm[b0 + bi][L + 1];
                const float hr = hsm[b0 + bi][L + 2];
                v0[bi] = 0.375f * hl + 0.625f * hc;
                v1[bi] = 0.125f * hl + 0.875f * hc;
                v2[bi] = 0.875f * hc + 0.125f * hr;
                v3[bi] = 0.625f * hc + 0.375f * hr;
            }
#pragma unroll
            for (int j = 0; j < 10; ++j) {
                const vfloat4 av = *(const vfloat4*)&asq[ch * 10 + j][L * 4];
#pragma unroll
                for (int bi = 0; bi < 8; ++bi) {
                    acc[bi][j] = fmaf(av.x, v0[bi], fmaf(av.y, v1[bi],
                                 fmaf(av.z, v2[bi], fmaf(av.w, v3[bi], acc[bi][j]))));
                }
            }
        }

        // cross-lane k-reduce: 80 values -> lane 63
        float r[8][10];
#pragma unroll
        for (int bi = 0; bi < 8; ++bi)
#pragma unroll
            for (int j = 0; j < 10; ++j) r[bi][j] = wave_sum63(acc[bi][j]);

        if (lane == 63) {
            float* pb = partial + (size_t)blk * 1280;
#pragma unroll
            for (int j = 0; j < 10; ++j) {
                const int nr = ch * 10 + j;
                vfloat4 lo = { r[0][j], r[1][j], r[2][j], r[3][j] };
                vfloat4 hi = { r[4][j], r[5][j], r[6][j], r[7][j] };
                *(vfloat4*)&pb[nr * 64 + w * 8]     = lo;
                *(vfloat4*)&pb[nr * 64 + w * 8 + 4] = hi;
            }
        }
    }
}

// ---------------------------------------------------------------------------
// k2a: reduce 8 k1-partials per block (coalesced columns). 64 blocks.
// ---------------------------------------------------------------------------
__global__ __launch_bounds__(256) void za_reduce1_kernel(
    const float* __restrict__ partial, float* __restrict__ partial2)
{
    const int j = blockIdx.x;
    const int t = threadIdx.x;
    for (int c = t; c < 1280; c += 256) {
        float s = 0.0f;
#pragma unroll
        for (int r = 0; r < 8; ++r)
            s += partial[(size_t)(8 * j + r) * 1280 + c];
        partial2[(size_t)j * 1280 + c] = s;
    }
}

// ---------------------------------------------------------------------------
// k2b: final column sum over 64 rows -> za[1280]
// ---------------------------------------------------------------------------
__global__ __launch_bounds__(256) void za_reduce2_kernel(
    const float* __restrict__ partial2, float* __restrict__ za)
{
    const int c = blockIdx.x * 256 + threadIdx.x;
    float s0 = 0.0f, s1 = 0.0f, s2 = 0.0f, s3 = 0.0f;
    for (int r = 0; r < 64; r += 4) {
        s0 += partial2[(size_t)r * 1280 + c];
        s1 += partial2[(size_t)(r + 1) * 1280 + c];
        s2 += partial2[(size_t)(r + 2) * 1280 + c];
        s3 += partial2[(size_t)(r + 3) * 1280 + c];
    }
    za[c] = (s0 + s1) + (s2 + s3);
}

// ---------------------------------------------------------------------------
// k3: z recurrence + out = z*C^T + bias. 512 blocks: 256 s-chunks x 2 b-halves.
// Non-temporal float4 stores (67 MB streaming output).
// ---------------------------------------------------------------------------
__global__ __launch_bounds__(256) void out_kernel(
    const float* __restrict__ C,      // (S,4)
    const float* __restrict__ bias,   // (S,)
    const float* __restrict__ za,     // (20,64) elem nr*64+b
    float* __restrict__ out)          // (64,S)
{
    __shared__ float zs[BATCH][4];
    const int t  = threadIdx.x;
    const int sb = blockIdx.x >> 1;   // s-chunk (1024 s)
    const int bh = blockIdx.x & 1;    // batch half

    if (t < 64) {
        const int bb = t;
#pragma unroll
        for (int r = 0; r < 4; ++r) {
            float zv = za[r * 64 + bb];                 // n = 0
#pragma unroll
            for (int n = 1; n < 5; ++n)
                zv *= (1.0f + za[(n * 4 + r) * 64 + bb]);
            zs[bb][r] = zv;
        }
    }
    __syncthreads();

    const int s0 = (sb * 256 + t) * 4;
    const vfloat4 c0 = *(const vfloat4*)(C + (size_t)s0 * 4);
    const vfloat4 c1 = *(const vfloat4*)(C + (size_t)s0 * 4 + 4);
    const vfloat4 c2 = *(const vfloat4*)(C + (size_t)s0 * 4 + 8);
    const vfloat4 c3 = *(const vfloat4*)(C + (size_t)s0 * 4 + 12);
    const vfloat4 bv = *(const vfloat4*)(bias + s0);

#pragma unroll 8
    for (int bb = bh * 32; bb < bh * 32 + 32; ++bb) {
        const float z0 = zs[bb][0], z1 = zs[bb][1];
        const float z2 = zs[bb][2], z3 = zs[bb][3];
        vfloat4 o;
        o.x = fmaf(z0, c0.x, fmaf(z1, c0.y, fmaf(z2, c0.z, fmaf(z3, c0.w, bv.x))));
        o.y = fmaf(z0, c1.x, fmaf(z1, c1.y, fmaf(z2, c1.z, fmaf(z3, c1.w, bv.y))));
        o.z = fmaf(z0, c2.x, fmaf(z1, c2.y, fmaf(z2, c2.z, fmaf(z3, c2.w, bv.z))));
        o.w = fmaf(z0, c3.x, fmaf(z1, c3.y, fmaf(z2, c3.z, fmaf(z3, c3.w, bv.w))));
        __builtin_nontemporal_store(o, (vfloat4*)(out + (size_t)bb * S_TOTAL + s0));
    }
}

// ---------------------------------------------------------------------------
extern "C" void kernel_launch(void* const* d_in, const int* in_sizes, int n_in,
                              void* d_out, int out_size, void* d_ws, size_t ws_size,
                              hipStream_t stream)
{
    const float* x    = (const float*)d_in[0];
    const float* A    = (const float*)d_in[1];
    const float* C    = (const float*)d_in[2];
    const float* bias = (const float*)d_in[3];
    float* out = (float*)d_out;

    float* partial  = (float*)d_ws;                          // 512*1280
    float* partial2 = partial + (size_t)NBLK_K1 * 1280;      // 64*1280
    float* za       = partial2 + (size_t)64 * 1280;          // 1280

    za_partial_kernel<<<NBLK_K1, 512, 0, stream>>>(x, A, partial);
    za_reduce1_kernel<<<64, 256, 0, stream>>>(partial, partial2);
    za_reduce2_kernel<<<5, 256, 0, stream>>>(partial2, za);
    out_kernel<<<512, 256, 0, stream>>>(C, bias, za, out);
}

// Round 5
// 49.915 us; speedup vs baseline: 3.5109x; 1.2729x over previous
//
#include <hip/hip_runtime.h>

#define S_TOTAL (512 * 512)     // 262144
#define BATCH 64
#define KTOT 65536              // 512 y * 128 j  (post-fold reduction length)

typedef float vfloat4 __attribute__((ext_vector_type(4)));

// ds_swizzle xor helpers (imm must be literal). BitMode: (xor<<10)|0x1f.
__device__ __forceinline__ float swz_x1(float v) {
    return __int_as_float(__builtin_amdgcn_ds_swizzle(__float_as_int(v), 0x041F));
}
__device__ __forceinline__ float swz_x2(float v) {
    return __int_as_float(__builtin_amdgcn_ds_swizzle(__float_as_int(v), 0x081F));
}
__device__ __forceinline__ float swz_x4(float v) {
    return __int_as_float(__builtin_amdgcn_ds_swizzle(__float_as_int(v), 0x101F));
}
__device__ __forceinline__ float swz_x8(float v) {
    return __int_as_float(__builtin_amdgcn_ds_swizzle(__float_as_int(v), 0x201F));
}

// ---------------------------------------------------------------------------
// pass1: x-dimension adjoint fold of A.  B1[nr,y,j] = sum_x wx(x,j) A[nr,y,x]
// Interior: 8 taps [0.125,0.375,0.625,0.875,0.875,0.625,0.375,0.125] at
// x = 4j-2..4j+5 (zero-padded); edges add the clamp-folded corrections.
// 2 A-rows per block, fully coalesced read/write. Pure memory-bound.
// ---------------------------------------------------------------------------
__global__ __launch_bounds__(256) void adjx_kernel(
    const float* __restrict__ A,      // (20, 512, 512) rows contiguous
    float* __restrict__ B1)           // (20, 512, 128)
{
    __shared__ float rows[1024];
    const int t = threadIdx.x;
    const size_t base = (size_t)blockIdx.x * 1024;
#pragma unroll
    for (int e = 0; e < 4; ++e) rows[t + 256 * e] = A[base + t + 256 * e];
    __syncthreads();

    const int r = t >> 7;             // which of the 2 rows
    const int j = t & 127;
    const float* Lr = &rows[r * 512];
    const int bidx = 4 * j - 2;
    const float w[8] = {0.125f, 0.375f, 0.625f, 0.875f,
                        0.875f, 0.625f, 0.375f, 0.125f};
    float s = 0.0f;
#pragma unroll
    for (int p = 0; p < 8; ++p) {
        const int ix = bidx + p;
        if (ix >= 0 && ix < 512) s = fmaf(w[p], Lr[ix], s);
    }
    if (j == 0)   s += 0.375f * Lr[0]   + 0.125f * Lr[1];
    if (j == 127) s += 0.125f * Lr[510] + 0.375f * Lr[511];

    B1[(size_t)blockIdx.x * 256 + t] = s;   // == (blk*2+r)*128 + j
}

// ---------------------------------------------------------------------------
// kB: za partials. 256 blocks x 512 thr; block owns K-chunk = 2 y-rows x 128 j.
// Stage y-lerped x rows in LDS (xs[64][256]); lane covers K as one float4.
// Wave w owns batches 8w..8w+7; acc[16][5] = (b-octet x 20 nr) per lane.
// Cross-lane k-reduce: halving-exchange tree (ds_swizzle xor1/2/4/8 on the
// LDS pipe, ~5 ops/value) + shfl_xor 16/32 finals; bit-reversed store map.
// ---------------------------------------------------------------------------
__global__ __launch_bounds__(512) void za_partial_kernel(
    const float* __restrict__ x,      // (64, 128, 128)
    const float* __restrict__ B1,     // (20, 65536)
    float* __restrict__ partial)      // (256, 1280) elem b*20+nr
{
    __shared__ float xs[BATCH][256];  // 64 KB
    const int t   = threadIdx.x;
    const int blk = blockIdx.x;
    const int y0  = blk * 2;

    // y-lerp params for the two local rows (scalars, no runtime-indexed array)
    float wy0a, wy1a, wy0b, wy1b; int t0a, t1a, t0b, t1b;
    {
        const float cya = (y0 + 0.5f) * 0.25f - 0.5f;
        const float fja = floorf(cya); const int jya = (int)fja;
        wy1a = cya - fja; wy0a = 1.0f - wy1a;
        t0a = min(max(jya, 0), 127); t1a = min(max(jya + 1, 0), 127);
        const float cyb = (y0 + 1.5f) * 0.25f - 0.5f;
        const float fjb = floorf(cyb); const int jyb = (int)fjb;
        wy1b = cyb - fjb; wy0b = 1.0f - wy1b;
        t0b = min(max(jyb, 0), 127); t1b = min(max(jyb + 1, 0), 127);
    }
#pragma unroll
    for (int i = 0; i < 32; ++i) {
        const int e  = t + 512 * i;
        const int b  = e >> 8;
        const int kl = e & 255;
        const int yl = kl >> 7;
        const int j  = kl & 127;
        const float wy0 = yl ? wy0b : wy0a;
        const float wy1 = yl ? wy1b : wy1a;
        const int   ty0 = yl ? t0b : t0a;
        const int   ty1 = yl ? t1b : t1a;
        xs[b][kl] = x[b * 16384 + ty0 * 128 + j] * wy0 +
                    x[b * 16384 + ty1 * 128 + j] * wy1;
    }
    __syncthreads();

    const int w    = t >> 6;
    const int lane = t & 63;
    const int b0   = w * 8;

    vfloat4 xv[8];
#pragma unroll
    for (int bi = 0; bi < 8; ++bi)
        xv[bi] = *(const vfloat4*)&xs[b0 + bi][4 * lane];   // ds_read_b128

    const size_t kbase = (size_t)blk * 256 + 4 * lane;
    float* pb = partial + (size_t)blk * 1280;
    const int lane1 = lane & 1, lane2 = lane & 2, lane4 = lane & 4, lane8 = lane & 8;

#pragma unroll
    for (int ch = 0; ch < 2; ++ch) {
        float acc[16][5];
#pragma unroll
        for (int v = 0; v < 16; ++v)
#pragma unroll
            for (int tt = 0; tt < 5; ++tt) acc[v][tt] = 0.0f;

#pragma unroll
        for (int tt = 0; tt < 5; ++tt)
#pragma unroll
            for (int par = 0; par < 2; ++par) {
                const int nr = ch * 10 + 2 * tt + par;
                const vfloat4 bq = *(const vfloat4*)(B1 + (size_t)nr * KTOT + kbase);
#pragma unroll
                for (int bi = 0; bi < 8; ++bi) {
                    acc[bi * 2 + par][tt] =
                        fmaf(bq.x, xv[bi].x, fmaf(bq.y, xv[bi].y,
                        fmaf(bq.z, xv[bi].z, fmaf(bq.w, xv[bi].w,
                             acc[bi * 2 + par][tt]))));
                }
            }

        // ---- halving-exchange tree: each stage pairs (lo, hi) value halves.
        float s1[8][5];
#pragma unroll
        for (int v = 0; v < 8; ++v)
#pragma unroll
            for (int tt = 0; tt < 5; ++tt) {
                const float u = acc[v][tt], h = acc[v + 8][tt];
                s1[v][tt] = (lane1 ? h : u) + swz_x1(lane1 ? u : h);
            }
        float s2[4][5];
#pragma unroll
        for (int v = 0; v < 4; ++v)
#pragma unroll
            for (int tt = 0; tt < 5; ++tt) {
                const float u = s1[v][tt], h = s1[v + 4][tt];
                s2[v][tt] = (lane2 ? h : u) + swz_x2(lane2 ? u : h);
            }
        float s3[2][5];
#pragma unroll
        for (int v = 0; v < 2; ++v)
#pragma unroll
            for (int tt = 0; tt < 5; ++tt) {
                const float u = s2[v][tt], h = s2[v + 2][tt];
                s3[v][tt] = (lane4 ? h : u) + swz_x4(lane4 ? u : h);
            }
        float s4[5];
#pragma unroll
        for (int tt = 0; tt < 5; ++tt) {
            const float u = s3[0][tt], h = s3[1][tt];
            s4[tt] = (lane8 ? h : u) + swz_x8(lane8 ? u : h);
        }
        // finals: lanes l and l^16 / l^32 hold the same value index
#pragma unroll
        for (int tt = 0; tt < 5; ++tt) {
            s4[tt] += __shfl_xor(s4[tt], 16, 64);
            s4[tt] += __shfl_xor(s4[tt], 32, 64);
        }

        // store: lane<16 holds value m = bit-reversal(lane low 4 bits)
        if (lane < 16) {
            const int m = ((lane & 1) << 3) | ((lane & 2) << 1) |
                          ((lane & 4) >> 1) | ((lane & 8) >> 3);
            float* dst = pb + (b0 + (m >> 1)) * 20 + ch * 10 + (m & 1);
#pragma unroll
            for (int tt = 0; tt < 5; ++tt) dst[2 * tt] = s4[tt];
        }
    }
}

// ---------------------------------------------------------------------------
// k2: za[c] = sum over 256 block-partials (b-major layout c = b*20+nr)
// ---------------------------------------------------------------------------
__global__ __launch_bounds__(256) void za_reduce_kernel(
    const float* __restrict__ partial, float* __restrict__ za)
{
    const int c = blockIdx.x * 256 + threadIdx.x;
    float a0 = 0, a1 = 0, a2 = 0, a3 = 0, a4 = 0, a5 = 0, a6 = 0, a7 = 0;
    for (int r = 0; r < 256; r += 8) {
        a0 += partial[(size_t)(r + 0) * 1280 + c];
        a1 += partial[(size_t)(r + 1) * 1280 + c];
        a2 += partial[(size_t)(r + 2) * 1280 + c];
        a3 += partial[(size_t)(r + 3) * 1280 + c];
        a4 += partial[(size_t)(r + 4) * 1280 + c];
        a5 += partial[(size_t)(r + 5) * 1280 + c];
        a6 += partial[(size_t)(r + 6) * 1280 + c];
        a7 += partial[(size_t)(r + 7) * 1280 + c];
    }
    za[c] = ((a0 + a1) + (a2 + a3)) + ((a4 + a5) + (a6 + a7));
}

// ---------------------------------------------------------------------------
// k3: z recurrence + out = z*C^T + bias. 256 blocks, full batch per block
// (C read exactly once). Non-temporal float4 stores.
// ---------------------------------------------------------------------------
__global__ __launch_bounds__(256) void out_kernel(
    const float* __restrict__ C,      // (S,4)
    const float* __restrict__ bias,   // (S,)
    const float* __restrict__ za,     // (64,20) b-major
    float* __restrict__ out)          // (64,S)
{
    __shared__ float zs[BATCH][4];
    const int t = threadIdx.x;
    if (t < 64) {
#pragma unroll
        for (int r = 0; r < 4; ++r) {
            float zv = za[t * 20 + r];                  // n = 0
#pragma unroll
            for (int n = 1; n < 5; ++n)
                zv *= (1.0f + za[t * 20 + n * 4 + r]);
            zs[t][r] = zv;
        }
    }
    __syncthreads();

    const int s0 = (blockIdx.x * 256 + t) * 4;
    const vfloat4 c0 = *(const vfloat4*)(C + (size_t)s0 * 4);
    const vfloat4 c1 = *(const vfloat4*)(C + (size_t)s0 * 4 + 4);
    const vfloat4 c2 = *(const vfloat4*)(C + (size_t)s0 * 4 + 8);
    const vfloat4 c3 = *(const vfloat4*)(C + (size_t)s0 * 4 + 12);
    const vfloat4 bv = *(const vfloat4*)(bias + s0);

#pragma unroll 8
    for (int bb = 0; bb < BATCH; ++bb) {
        const float z0 = zs[bb][0], z1 = zs[bb][1];
        const float z2 = zs[bb][2], z3 = zs[bb][3];
        vfloat4 o;
        o.x = fmaf(z0, c0.x, fmaf(z1, c0.y, fmaf(z2, c0.z, fmaf(z3, c0.w, bv.x))));
        o.y = fmaf(z0, c1.x, fmaf(z1, c1.y, fmaf(z2, c1.z, fmaf(z3, c1.w, bv.y))));
        o.z = fmaf(z0, c2.x, fmaf(z1, c2.y, fmaf(z2, c2.z, fmaf(z3, c2.w, bv.z))));
        o.w = fmaf(z0, c3.x, fmaf(z1, c3.y, fmaf(z2, c3.z, fmaf(z3, c3.w, bv.w))));
        __builtin_nontemporal_store(o, (vfloat4*)(out + (size_t)bb * S_TOTAL + s0));
    }
}

// ---------------------------------------------------------------------------
extern "C" void kernel_launch(void* const* d_in, const int* in_sizes, int n_in,
                              void* d_out, int out_size, void* d_ws, size_t ws_size,
                              hipStream_t stream)
{
    const float* x    = (const float*)d_in[0];
    const float* A    = (const float*)d_in[1];
    const float* C    = (const float*)d_in[2];
    const float* bias = (const float*)d_in[3];
    float* out = (float*)d_out;

    float* B1      = (float*)d_ws;                        // 20*65536 = 5.24 MB
    float* partial = B1 + (size_t)20 * KTOT;              // 256*1280  = 1.31 MB
    float* za      = partial + (size_t)256 * 1280;        // 1280

    adjx_kernel<<<5120, 256, 0, stream>>>(A, B1);
    za_partial_kernel<<<256, 512, 0, stream>>>(x, B1, partial);
    za_reduce_kernel<<<5, 256, 0, stream>>>(partial, za);
    out_kernel<<<256, 256, 0, stream>>>(C, bias, za, out);
}

// Round 6
// 37.261 us; speedup vs baseline: 4.7032x; 1.3396x over previous
//
#include <hip/hip_runtime.h>

#define S_TOTAL (512 * 512)     // 262144
#define BATCH 64
#define KTOT 65536              // after x-fold: 512 y * 128 j
#define KTOT2 16384             // after y-fold: 128 ty * 128 j

typedef float vfloat4 __attribute__((ext_vector_type(4)));

// ds_swizzle xor helpers (imm must be literal). BitMode: (xor<<10)|0x1f.
__device__ __forceinline__ float swz_x1(float v) {
    return __int_as_float(__builtin_amdgcn_ds_swizzle(__float_as_int(v), 0x041F));
}
__device__ __forceinline__ float swz_x2(float v) {
    return __int_as_float(__builtin_amdgcn_ds_swizzle(__float_as_int(v), 0x081F));
}
__device__ __forceinline__ float swz_x4(float v) {
    return __int_as_float(__builtin_amdgcn_ds_swizzle(__float_as_int(v), 0x101F));
}
__device__ __forceinline__ float swz_x8(float v) {
    return __int_as_float(__builtin_amdgcn_ds_swizzle(__float_as_int(v), 0x201F));
}

// ---------------------------------------------------------------------------
// pass1: x-adjoint fold.  B1[nr,y,j] = sum_x wx(x,j) A[nr,y,x]
// 8 taps [1,3,5,7,7,5,3,1]/8 at x=4j-2..4j+5 (zero-padded) + edge corrections.
// ---------------------------------------------------------------------------
__global__ __launch_bounds__(256) void adjx_kernel(
    const float* __restrict__ A,      // (20, 512, 512)
    float* __restrict__ B1)           // (20, 512, 128)
{
    __shared__ float rows[1024];
    const int t = threadIdx.x;
    const size_t base = (size_t)blockIdx.x * 1024;
#pragma unroll
    for (int e = 0; e < 4; ++e) rows[t + 256 * e] = A[base + t + 256 * e];
    __syncthreads();

    const int r = t >> 7;
    const int j = t & 127;
    const float* Lr = &rows[r * 512];
    const int bidx = 4 * j - 2;
    const float w[8] = {0.125f, 0.375f, 0.625f, 0.875f,
                        0.875f, 0.625f, 0.375f, 0.125f};
    float s = 0.0f;
#pragma unroll
    for (int p = 0; p < 8; ++p) {
        const int ix = bidx + p;
        if (ix >= 0 && ix < 512) s = fmaf(w[p], Lr[ix], s);
    }
    if (j == 0)   s += 0.375f * Lr[0]   + 0.125f * Lr[1];
    if (j == 127) s += 0.125f * Lr[510] + 0.375f * Lr[511];

    B1[(size_t)blockIdx.x * 256 + t] = s;
}

// ---------------------------------------------------------------------------
// pass2: y-adjoint fold.  B2[nr,ty,j] = sum_y wy(y,ty) B1[nr,y,j]
// Identical tap/edge structure, along y (stride 128). 2560 blocks x 128 thr.
// ---------------------------------------------------------------------------
__global__ __launch_bounds__(128) void adjy_kernel(
    const float* __restrict__ B1,     // (20, 512, 128)
    float* __restrict__ B2)           // (20, 128, 128)
{
    const int j  = threadIdx.x;
    const int ty = blockIdx.x & 127;
    const int nr = blockIdx.x >> 7;
    const float* Bn = B1 + (size_t)nr * KTOT;
    const int biy = 4 * ty - 2;
    const float w[8] = {0.125f, 0.375f, 0.625f, 0.875f,
                        0.875f, 0.625f, 0.375f, 0.125f};
    float s = 0.0f;
#pragma unroll
    for (int p = 0; p < 8; ++p) {
        const int iy = biy + p;
        if (iy >= 0 && iy < 512) s = fmaf(w[p], Bn[iy * 128 + j], s);
    }
    if (ty == 0)   s += 0.375f * Bn[j]             + 0.125f * Bn[128 + j];
    if (ty == 127) s += 0.125f * Bn[510 * 128 + j] + 0.375f * Bn[511 * 128 + j];

    B2[(size_t)nr * KTOT2 + ty * 128 + j] = s;
}

// ---------------------------------------------------------------------------
// pass3: za partials = B2 (20 x 16384) . x^T (64 x 16384).
// 64 blocks x 512 thr; block owns K-chunk of 256 (lane = float4 of k).
// Wave w owns batches 8w..8w+7. x consumed directly (no upsample!).
// Cross-lane reduce: halving-exchange tree (swizzle xor 1/2/4/8 + shfl 16/32).
// ---------------------------------------------------------------------------
__global__ __launch_bounds__(512) void za_partial_kernel(
    const float* __restrict__ x,      // (64, 16384)
    const float* __restrict__ B2,     // (20, 16384)
    float* __restrict__ partial)      // (64, 1280) elem b*20+nr
{
    const int t    = threadIdx.x;
    const int blk  = blockIdx.x;
    const int w    = t >> 6;
    const int lane = t & 63;
    const int b0   = w * 8;
    const size_t kbase = (size_t)blk * 256 + 4 * lane;

    vfloat4 xv[8];
#pragma unroll
    for (int bi = 0; bi < 8; ++bi)
        xv[bi] = *(const vfloat4*)(x + (size_t)(b0 + bi) * KTOT2 + kbase);

    float* pb = partial + (size_t)blk * 1280;
    const int lane1 = lane & 1, lane2 = lane & 2, lane4 = lane & 4, lane8 = lane & 8;

#pragma unroll
    for (int ch = 0; ch < 2; ++ch) {
        float acc[16][5];
#pragma unroll
        for (int v = 0; v < 16; ++v)
#pragma unroll
            for (int tt = 0; tt < 5; ++tt) acc[v][tt] = 0.0f;

#pragma unroll
        for (int tt = 0; tt < 5; ++tt)
#pragma unroll
            for (int par = 0; par < 2; ++par) {
                const int nr = ch * 10 + 2 * tt + par;
                const vfloat4 bq = *(const vfloat4*)(B2 + (size_t)nr * KTOT2 + kbase);
#pragma unroll
                for (int bi = 0; bi < 8; ++bi) {
                    acc[bi * 2 + par][tt] =
                        fmaf(bq.x, xv[bi].x, fmaf(bq.y, xv[bi].y,
                        fmaf(bq.z, xv[bi].z, fmaf(bq.w, xv[bi].w,
                             acc[bi * 2 + par][tt]))));
                }
            }

        float s1[8][5];
#pragma unroll
        for (int v = 0; v < 8; ++v)
#pragma unroll
            for (int tt = 0; tt < 5; ++tt) {
                const float u = acc[v][tt], h = acc[v + 8][tt];
                s1[v][tt] = (lane1 ? h : u) + swz_x1(lane1 ? u : h);
            }
        float s2[4][5];
#pragma unroll
        for (int v = 0; v < 4; ++v)
#pragma unroll
            for (int tt = 0; tt < 5; ++tt) {
                const float u = s1[v][tt], h = s1[v + 4][tt];
                s2[v][tt] = (lane2 ? h : u) + swz_x2(lane2 ? u : h);
            }
        float s3[2][5];
#pragma unroll
        for (int v = 0; v < 2; ++v)
#pragma unroll
            for (int tt = 0; tt < 5; ++tt) {
                const float u = s2[v][tt], h = s2[v + 2][tt];
                s3[v][tt] = (lane4 ? h : u) + swz_x4(lane4 ? u : h);
            }
        float s4[5];
#pragma unroll
        for (int tt = 0; tt < 5; ++tt) {
            const float u = s3[0][tt], h = s3[1][tt];
            s4[tt] = (lane8 ? h : u) + swz_x8(lane8 ? u : h);
        }
#pragma unroll
        for (int tt = 0; tt < 5; ++tt) {
            s4[tt] += __shfl_xor(s4[tt], 16, 64);
            s4[tt] += __shfl_xor(s4[tt], 32, 64);
        }

        if (lane < 16) {
            const int m = ((lane & 1) << 3) | ((lane & 2) << 1) |
                          ((lane & 4) >> 1) | ((lane & 8) >> 3);
            float* dst = pb + (b0 + (m >> 1)) * 20 + ch * 10 + (m & 1);
#pragma unroll
            for (int tt = 0; tt < 5; ++tt) dst[2 * tt] = s4[tt];
        }
    }
}

// ---------------------------------------------------------------------------
// pass4: za[c] = sum over 64 block-partials (c = b*20+nr)
// ---------------------------------------------------------------------------
__global__ __launch_bounds__(256) void za_reduce_kernel(
    const float* __restrict__ partial, float* __restrict__ za)
{
    const int c = blockIdx.x * 256 + threadIdx.x;
    float a0 = 0, a1 = 0, a2 = 0, a3 = 0;
    for (int r = 0; r < 64; r += 4) {
        a0 += partial[(size_t)(r + 0) * 1280 + c];
        a1 += partial[(size_t)(r + 1) * 1280 + c];
        a2 += partial[(size_t)(r + 2) * 1280 + c];
        a3 += partial[(size_t)(r + 3) * 1280 + c];
    }
    za[c] = (a0 + a1) + (a2 + a3);
}

// ---------------------------------------------------------------------------
// pass5: z recurrence + out = z*C^T + bias. 256 blocks, full batch per block
// (C read exactly once). Non-temporal float4 stores.
// ---------------------------------------------------------------------------
__global__ __launch_bounds__(256) void out_kernel(
    const float* __restrict__ C,      // (S,4)
    const float* __restrict__ bias,   // (S,)
    const float* __restrict__ za,     // (64,20) b-major
    float* __restrict__ out)          // (64,S)
{
    __shared__ float zs[BATCH][4];
    const int t = threadIdx.x;
    if (t < 64) {
#pragma unroll
        for (int r = 0; r < 4; ++r) {
            float zv = za[t * 20 + r];                  // n = 0
#pragma unroll
            for (int n = 1; n < 5; ++n)
                zv *= (1.0f + za[t * 20 + n * 4 + r]);
            zs[t][r] = zv;
        }
    }
    __syncthreads();

    const int s0 = (blockIdx.x * 256 + t) * 4;
    const vfloat4 c0 = *(const vfloat4*)(C + (size_t)s0 * 4);
    const vfloat4 c1 = *(const vfloat4*)(C + (size_t)s0 * 4 + 4);
    const vfloat4 c2 = *(const vfloat4*)(C + (size_t)s0 * 4 + 8);
    const vfloat4 c3 = *(const vfloat4*)(C + (size_t)s0 * 4 + 12);
    const vfloat4 bv = *(const vfloat4*)(bias + s0);

#pragma unroll 8
    for (int bb = 0; bb < BATCH; ++bb) {
        const float z0 = zs[bb][0], z1 = zs[bb][1];
        const float z2 = zs[bb][2], z3 = zs[bb][3];
        vfloat4 o;
        o.x = fmaf(z0, c0.x, fmaf(z1, c0.y, fmaf(z2, c0.z, fmaf(z3, c0.w, bv.x))));
        o.y = fmaf(z0, c1.x, fmaf(z1, c1.y, fmaf(z2, c1.z, fmaf(z3, c1.w, bv.y))));
        o.z = fmaf(z0, c2.x, fmaf(z1, c2.y, fmaf(z2, c2.z, fmaf(z3, c2.w, bv.z))));
        o.w = fmaf(z0, c3.x, fmaf(z1, c3.y, fmaf(z2, c3.z, fmaf(z3, c3.w, bv.w))));
        __builtin_nontemporal_store(o, (vfloat4*)(out + (size_t)bb * S_TOTAL + s0));
    }
}

// ---------------------------------------------------------------------------
extern "C" void kernel_launch(void* const* d_in, const int* in_sizes, int n_in,
                              void* d_out, int out_size, void* d_ws, size_t ws_size,
                              hipStream_t stream)
{
    const float* x    = (const float*)d_in[0];
    const float* A    = (const float*)d_in[1];
    const float* C    = (const float*)d_in[2];
    const float* bias = (const float*)d_in[3];
    float* out = (float*)d_out;

    float* B1      = (float*)d_ws;                        // 20*65536 = 5.24 MB
    float* B2      = B1 + (size_t)20 * KTOT;              // 20*16384 = 1.31 MB
    float* partial = B2 + (size_t)20 * KTOT2;             // 64*1280
    float* za      = partial + (size_t)64 * 1280;         // 1280

    adjx_kernel<<<5120, 256, 0, stream>>>(A, B1);
    adjy_kernel<<<2560, 128, 0, stream>>>(B1, B2);
    za_partial_kernel<<<64, 512, 0, stream>>>(x, B2, partial);
    za_reduce_kernel<<<5, 256, 0, stream>>>(partial, za);
    out_kernel<<<256, 256, 0, stream>>>(C, bias, za, out);
}

// Round 7
// 35.874 us; speedup vs baseline: 4.8850x; 1.0387x over previous
//
#include <hip/hip_runtime.h>

#define S_TOTAL (512 * 512)     // 262144
#define BATCH 64
#define KTOT2 16384             // 128 ty * 128 j  (fully folded K)

typedef float vfloat4 __attribute__((ext_vector_type(4)));
typedef float vfloat2 __attribute__((ext_vector_type(2)));

// ds_swizzle xor helpers (imm must be literal). BitMode: (xor<<10)|0x1f.
__device__ __forceinline__ float swz_x1(float v) {
    return __int_as_float(__builtin_amdgcn_ds_swizzle(__float_as_int(v), 0x041F));
}
__device__ __forceinline__ float swz_x2(float v) {
    return __int_as_float(__builtin_amdgcn_ds_swizzle(__float_as_int(v), 0x081F));
}
__device__ __forceinline__ float swz_x4(float v) {
    return __int_as_float(__builtin_amdgcn_ds_swizzle(__float_as_int(v), 0x101F));
}
__device__ __forceinline__ float swz_x8(float v) {
    return __int_as_float(__builtin_amdgcn_ds_swizzle(__float_as_int(v), 0x201F));
}

// ---------------------------------------------------------------------------
// pass1 (fused): A -> B2.  B2[nr,ty,j] = sum_y wy(y,ty) sum_x wx(x,j) A[nr,y,x]
// Block = (nr, ty-chunk of 4). Stages 20 A-rows (y = 16*tc-2 .. +17, zero-pad
// outside [0,512)) in LDS, x-folds into b1loc[20][128], y-folds 512 outputs.
// x-fold reads 3 aligned float4 LDS words per output (conflict-free b128).
// Zero-padded rows make the y-fold range-check-free; edge corrections match
// the proven adjx/adjy kernels exactly.
// ---------------------------------------------------------------------------
__global__ __launch_bounds__(256) void adjxy_kernel(
    const float* __restrict__ A,      // (20, 512, 512)
    float* __restrict__ B2)           // (20, 128, 128)
{
    __shared__ float arows[20][512];  // 40 KB
    __shared__ float b1loc[20][128];  // 10 KB

    const int t  = threadIdx.x;
    const int nr = blockIdx.x >> 5;   // 0..19
    const int tc = blockIdx.x & 31;   // ty-chunk 0..31
    const int y0 = 16 * tc - 2;       // global y of local row 0

    // ---- stage A rows (float4 coalesced, zero-pad invalid y)
    const float* An = A + (size_t)nr * S_TOTAL;
#pragma unroll
    for (int i = t; i < 20 * 128; i += 256) {
        const int rl = i >> 7;
        const int q  = i & 127;
        const int y  = y0 + rl;
        vfloat4 v = {0.0f, 0.0f, 0.0f, 0.0f};
        if (y >= 0 && y < 512)
            v = *(const vfloat4*)(An + (size_t)y * 512 + q * 4);
        *(vfloat4*)&arows[rl][q * 4] = v;
    }
    __syncthreads();

    // ---- x-fold: b1loc[rl][j] = sum_p wx[p] * arows[rl][4j-2+p] (+ edges)
#pragma unroll
    for (int i = t; i < 20 * 128; i += 256) {
        const int rl = i >> 7;
        const int j  = i & 127;
        const int base = 4 * j;
        const vfloat4 m0 = *(const vfloat4*)&arows[rl][max(base - 4, 0)];
        const vfloat4 m1 = *(const vfloat4*)&arows[rl][base];
        const vfloat4 m2 = *(const vfloat4*)&arows[rl][min(base + 4, 508)];
        // window 4j-2..4j+5 = m0.z, m0.w, m1.xyzw, m2.x, m2.y
        float e0 = m0.z, e1 = m0.w, e6 = m2.x, e7 = m2.y;
        if (j == 0)   { e0 = 0.0f; e1 = 0.0f; }
        if (j == 127) { e6 = 0.0f; e7 = 0.0f; }
        float s = 0.125f * e0 + 0.375f * e1
                + 0.625f * m1.x + 0.875f * m1.y
                + 0.875f * m1.z + 0.625f * m1.w
                + 0.375f * e6 + 0.125f * e7;
        if (j == 0)   s += 0.375f * arows[rl][0]   + 0.125f * arows[rl][1];
        if (j == 127) s += 0.125f * arows[rl][510] + 0.375f * arows[rl][511];
        b1loc[rl][j] = s;
    }
    __syncthreads();

    // ---- y-fold: B2[ty][j] = sum_p wy[p] * b1loc[4*tyl+p][j] (+ edges)
    const float w[8] = {0.125f, 0.375f, 0.625f, 0.875f,
                        0.875f, 0.625f, 0.375f, 0.125f};
#pragma unroll
    for (int i = t; i < 512; i += 256) {
        const int tyl = i >> 7;
        const int j   = i & 127;
        const int ty  = tc * 4 + tyl;
        float s = 0.0f;
#pragma unroll
        for (int p = 0; p < 8; ++p)
            s = fmaf(w[p], b1loc[4 * tyl + p][j], s);
        // zero-padded rows contribute 0 automatically; add edge corrections
        if (ty == 0)   s += 0.375f * b1loc[2][j]  + 0.125f * b1loc[3][j];   // y=0,1
        if (ty == 127) s += 0.125f * b1loc[16][j] + 0.375f * b1loc[17][j];  // y=510,511
        B2[(size_t)nr * KTOT2 + ty * 128 + j] = s;
    }
}

// ---------------------------------------------------------------------------
// pass2: za partials = B2 (20 x 16384) . x^T (64 x 16384).
// 64 blocks x 512 thr; block owns K-chunk of 256 (lane = float4 of k).
// Wave w owns batches 8w..8w+7. Cross-lane reduce: halving-exchange tree.
// ---------------------------------------------------------------------------
__global__ __launch_bounds__(512) void za_partial_kernel(
    const float* __restrict__ x,      // (64, 16384)
    const float* __restrict__ B2,     // (20, 16384)
    float* __restrict__ partial)      // (64, 1280) elem b*20+nr
{
    const int t    = threadIdx.x;
    const int blk  = blockIdx.x;
    const int w    = t >> 6;
    const int lane = t & 63;
    const int b0   = w * 8;
    const size_t kbase = (size_t)blk * 256 + 4 * lane;

    vfloat4 xv[8];
#pragma unroll
    for (int bi = 0; bi < 8; ++bi)
        xv[bi] = *(const vfloat4*)(x + (size_t)(b0 + bi) * KTOT2 + kbase);

    float* pb = partial + (size_t)blk * 1280;
    const int lane1 = lane & 1, lane2 = lane & 2, lane4 = lane & 4, lane8 = lane & 8;

#pragma unroll
    for (int ch = 0; ch < 2; ++ch) {
        float acc[16][5];
#pragma unroll
        for (int v = 0; v < 16; ++v)
#pragma unroll
            for (int tt = 0; tt < 5; ++tt) acc[v][tt] = 0.0f;

#pragma unroll
        for (int tt = 0; tt < 5; ++tt)
#pragma unroll
            for (int par = 0; par < 2; ++par) {
                const int nr = ch * 10 + 2 * tt + par;
                const vfloat4 bq = *(const vfloat4*)(B2 + (size_t)nr * KTOT2 + kbase);
#pragma unroll
                for (int bi = 0; bi < 8; ++bi) {
                    acc[bi * 2 + par][tt] =
                        fmaf(bq.x, xv[bi].x, fmaf(bq.y, xv[bi].y,
                        fmaf(bq.z, xv[bi].z, fmaf(bq.w, xv[bi].w,
                             acc[bi * 2 + par][tt]))));
                }
            }

        float s1[8][5];
#pragma unroll
        for (int v = 0; v < 8; ++v)
#pragma unroll
            for (int tt = 0; tt < 5; ++tt) {
                const float u = acc[v][tt], h = acc[v + 8][tt];
                s1[v][tt] = (lane1 ? h : u) + swz_x1(lane1 ? u : h);
            }
        float s2[4][5];
#pragma unroll
        for (int v = 0; v < 4; ++v)
#pragma unroll
            for (int tt = 0; tt < 5; ++tt) {
                const float u = s1[v][tt], h = s1[v + 4][tt];
                s2[v][tt] = (lane2 ? h : u) + swz_x2(lane2 ? u : h);
            }
        float s3[2][5];
#pragma unroll
        for (int v = 0; v < 2; ++v)
#pragma unroll
            for (int tt = 0; tt < 5; ++tt) {
                const float u = s2[v][tt], h = s2[v + 2][tt];
                s3[v][tt] = (lane4 ? h : u) + swz_x4(lane4 ? u : h);
            }
        float s4[5];
#pragma unroll
        for (int tt = 0; tt < 5; ++tt) {
            const float u = s3[0][tt], h = s3[1][tt];
            s4[tt] = (lane8 ? h : u) + swz_x8(lane8 ? u : h);
        }
#pragma unroll
        for (int tt = 0; tt < 5; ++tt) {
            s4[tt] += __shfl_xor(s4[tt], 16, 64);
            s4[tt] += __shfl_xor(s4[tt], 32, 64);
        }

        if (lane < 16) {
            const int m = ((lane & 1) << 3) | ((lane & 2) << 1) |
                          ((lane & 4) >> 1) | ((lane & 8) >> 3);
            float* dst = pb + (b0 + (m >> 1)) * 20 + ch * 10 + (m & 1);
#pragma unroll
            for (int tt = 0; tt < 5; ++tt) dst[2 * tt] = s4[tt];
        }
    }
}

// ---------------------------------------------------------------------------
// pass3: za[c] = sum over 64 block-partials (c = b*20+nr)
// ---------------------------------------------------------------------------
__global__ __launch_bounds__(256) void za_reduce_kernel(
    const float* __restrict__ partial, float* __restrict__ za)
{
    const int c = blockIdx.x * 256 + threadIdx.x;
    float a0 = 0, a1 = 0, a2 = 0, a3 = 0;
    for (int r = 0; r < 64; r += 4) {
        a0 += partial[(size_t)(r + 0) * 1280 + c];
        a1 += partial[(size_t)(r + 1) * 1280 + c];
        a2 += partial[(size_t)(r + 2) * 1280 + c];
        a3 += partial[(size_t)(r + 3) * 1280 + c];
    }
    za[c] = (a0 + a1) + (a2 + a3);
}

// ---------------------------------------------------------------------------
// pass4: z recurrence + out = z*C^T + bias. 512 blocks x 256 thr, thread owns
// an s-pair, full batch per block (C read exactly once). float2 NT stores.
// ---------------------------------------------------------------------------
__global__ __launch_bounds__(256) void out_kernel(
    const float* __restrict__ C,      // (S,4)
    const float* __restrict__ bias,   // (S,)
    const float* __restrict__ za,     // (64,20) b-major
    float* __restrict__ out)          // (64,S)
{
    __shared__ float zs[BATCH][4];
    const int t = threadIdx.x;
    if (t < 64) {
#pragma unroll
        for (int r = 0; r < 4; ++r) {
            float zv = za[t * 20 + r];                  // n = 0
#pragma unroll
            for (int n = 1; n < 5; ++n)
                zv *= (1.0f + za[t * 20 + n * 4 + r]);
            zs[t][r] = zv;
        }
    }
    __syncthreads();

    const int s0 = (blockIdx.x * 256 + t) * 2;
    const vfloat4 c0 = *(const vfloat4*)(C + (size_t)s0 * 4);
    const vfloat4 c1 = *(const vfloat4*)(C + (size_t)s0 * 4 + 4);
    const vfloat2 bv = *(const vfloat2*)(bias + s0);

#pragma unroll 8
    for (int bb = 0; bb < BATCH; ++bb) {
        const float z0 = zs[bb][0], z1 = zs[bb][1];
        const float z2 = zs[bb][2], z3 = zs[bb][3];
        vfloat2 o;
        o.x = fmaf(z0, c0.x, fmaf(z1, c0.y, fmaf(z2, c0.z, fmaf(z3, c0.w, bv.x))));
        o.y = fmaf(z0, c1.x, fmaf(z1, c1.y, fmaf(z2, c1.z, fmaf(z3, c1.w, bv.y))));
        __builtin_nontemporal_store(o, (vfloat2*)(out + (size_t)bb * S_TOTAL + s0));
    }
}

// ---------------------------------------------------------------------------
extern "C" void kernel_launch(void* const* d_in, const int* in_sizes, int n_in,
                              void* d_out, int out_size, void* d_ws, size_t ws_size,
                              hipStream_t stream)
{
    const float* x    = (const float*)d_in[0];
    const float* A    = (const float*)d_in[1];
    const float* C    = (const float*)d_in[2];
    const float* bias = (const float*)d_in[3];
    float* out = (float*)d_out;

    float* B2      = (float*)d_ws;                        // 20*16384 = 1.31 MB
    float* partial = B2 + (size_t)20 * KTOT2;             // 64*1280
    float* za      = partial + (size_t)64 * 1280;         // 1280

    adjxy_kernel<<<640, 256, 0, stream>>>(A, B2);
    za_partial_kernel<<<64, 512, 0, stream>>>(x, B2, partial);
    za_reduce_kernel<<<5, 256, 0, stream>>>(partial, za);
    out_kernel<<<512, 256, 0, stream>>>(C, bias, za, out);
}